// Round 1
// baseline (421.386 us; speedup 1.0000x reference)
//
#include <hip/hip_runtime.h>
#include <hip/hip_bf16.h>
#include <math.h>

typedef __attribute__((ext_vector_type(4))) float  f32x4;
typedef __attribute__((ext_vector_type(4))) int    i32x4;
typedef __attribute__((ext_vector_type(8))) short  s16x8;
typedef __attribute__((ext_vector_type(4))) short  s16x4;
typedef __attribute__((ext_vector_type(8))) __bf16 bf16x8;

#define LOG2E 1.4426950408889634f

__device__ __forceinline__ short f32_to_bf16_rne(float f) {
    unsigned u = __builtin_bit_cast(unsigned, f);
    u += 0x7fffu + ((u >> 16) & 1u);
    return (short)(u >> 16);
}
__device__ __forceinline__ bf16x8 as_bf16x8(s16x8 v) {
    return __builtin_bit_cast(bf16x8, v);
}

// ---------------- k0: W (f32 [k][col]) -> WT bf16 [col][k] ----------------
__global__ void k0_wt(const float* __restrict__ W, short* __restrict__ WT) {
    int g = blockIdx.x * 256 + threadIdx.x;     // 0..8191
    int col = g >> 6;
    int k0 = (g & 63) * 4;
    s16x4 v;
    #pragma unroll
    for (int i = 0; i < 4; ++i) v[i] = f32_to_bf16_rne(W[(k0 + i) * 128 + col]);
    *(s16x4*)(WT + col * 256 + k0) = v;
}

// ---------------- k1: Wh = h@W (MFMA), emit WhT bf16 [b][col][n], Wh1', Wh2' ----------------
__global__ __launch_bounds__(256, 2) void k1_gemm(
    const float* __restrict__ h, const float* __restrict__ a,
    const short* __restrict__ WT,
    short* __restrict__ WhT, float* __restrict__ Wh1p, float* __restrict__ Tp)
{
    int l = threadIdx.x & 63;
    int w = threadIdx.x >> 6;
    int gw = blockIdx.x * 4 + w;
    int r0 = gw * 16;                  // global row base (b*4096+n), multiple of 16
    int lm = l & 15, q = l >> 4;

    f32x4 acc[8];
    #pragma unroll
    for (int ct = 0; ct < 8; ++ct) acc[ct] = (f32x4)0.0f;

    const float* hrow = h + (long)(r0 + lm) * 256;
    for (int kb = 0; kb < 8; ++kb) {
        int kbase = kb * 32 + q * 8;
        f32x4 h0 = *(const f32x4*)(hrow + kbase);
        f32x4 h1 = *(const f32x4*)(hrow + kbase + 4);
        s16x8 af;
        #pragma unroll
        for (int j = 0; j < 4; ++j) af[j] = f32_to_bf16_rne(h0[j]);
        #pragma unroll
        for (int j = 0; j < 4; ++j) af[4 + j] = f32_to_bf16_rne(h1[j]);
        bf16x8 afb = as_bf16x8(af);
        #pragma unroll
        for (int ct = 0; ct < 8; ++ct) {
            s16x8 bf = *(const s16x8*)(WT + (ct * 16 + lm) * 256 + kbase);
            acc[ct] = __builtin_amdgcn_mfma_f32_16x16x32_bf16(afb, as_bf16x8(bf), acc[ct], 0, 0, 0);
        }
    }

    int b = r0 >> 12;
    int nb = r0 & 4095;
    float p1[4] = {0.f, 0.f, 0.f, 0.f}, p2[4] = {0.f, 0.f, 0.f, 0.f};
    #pragma unroll
    for (int ct = 0; ct < 8; ++ct) {
        int col = ct * 16 + lm;
        float a1c = a[col], a2c = a[128 + col];
        s16x4 vv;
        #pragma unroll
        for (int r = 0; r < 4; ++r) {
            float v = acc[ct][r];
            p1[r] += v * a1c;
            p2[r] += v * a2c;
            vv[r] = f32_to_bf16_rne(v);
        }
        // C/D rows = q*4+r (contiguous n): one 8B store per col
        *(s16x4*)(WhT + ((long)(b * 128 + col) * 4096 + nb + q * 4)) = vv;
    }
    #pragma unroll
    for (int off = 1; off < 16; off <<= 1) {
        #pragma unroll
        for (int r = 0; r < 4; ++r) {
            p1[r] += __shfl_xor(p1[r], off);
            p2[r] += __shfl_xor(p2[r], off);
        }
    }
    if (lm == 0) {
        #pragma unroll
        for (int r = 0; r < 4; ++r) {
            int row = r0 + q * 4 + r;
            Wh1p[row] = LOG2E * p1[r];
            Tp[row]   = LOG2E * p2[r];
        }
    }
}

// ---------------- k2: per-batch max of Tp ----------------
__global__ void k2_tmax(const float* __restrict__ Tp, float* __restrict__ Tmax) {
    __shared__ float red[256];
    int b = blockIdx.x, t = threadIdx.x;
    float mx = -1e30f;
    for (int i = 0; i < 16; ++i) mx = fmaxf(mx, Tp[b * 4096 + t + i * 256]);
    red[t] = mx;
    __syncthreads();
    for (int s = 128; s > 0; s >>= 1) {
        if (t < s) red[t] = fmaxf(red[t], red[t + s]);
        __syncthreads();
    }
    if (t == 0) Tmax[b] = red[0];
}

// ---------------- k3: masked-softmax attention @ Wh (flash-style, fixed max) ----------------
template <int SPLIT, bool DIRECT>
__global__ __launch_bounds__(256, 2) void k3_attn(
    const int* __restrict__ adj, const short* __restrict__ WhT,
    const float* __restrict__ Wh1p, const float* __restrict__ Tp,
    const float* __restrict__ Tmax,
    float* __restrict__ U, float* __restrict__ Z, float* __restrict__ out)
{
    __shared__ __align__(16) short tile[128 * 128];   // [col][m-chunk swizzled], 32 KB
    int bid = blockIdx.x;
    int mh = bid % SPLIT;
    int nt = (bid / SPLIT) & 63;
    int b  = bid / (SPLIT * 64);
    int n0 = nt * 64;
    int l = threadIdx.x & 63, w = threadIdx.x >> 6;
    int lm = l & 15, q = l >> 4;

    int n_lane = n0 + w * 16 + lm;                   // A-row this lane feeds
    float sp  = Wh1p[b * 4096 + n_lane];             // log2e * Wh1[n]
    float xm  = sp + Tmax[b];
    float Mrow = fmaxf(xm, 0.2f * xm);               // fixed per-row softmax max (scaled)

    const int MTILES = 4096 / (SPLIT * 128);
    int mbase0 = mh * (4096 / SPLIT);

    const int*   adjrow = adj + ((long)(b * 4096 + n_lane) << 12);
    const float* tpb    = Tp + b * 4096;
    const short* whtb   = WhT + (long)b * 128 * 4096;

    f32x4 acc[8];
    #pragma unroll
    for (int ct = 0; ct < 8; ++ct) acc[ct] = (f32x4)0.0f;
    float z = 0.0f;

    #pragma unroll 1
    for (int ti = 0; ti < MTILES; ++ti) {
        int m0 = mbase0 + ti * 128;
        __syncthreads();   // all waves done reading previous tile
        // stage WhT tile via global_load_lds (16B/lane), XOR-swizzled chunks
        {
            int colw = w * 32;
            #pragma unroll
            for (int j = 0; j < 8; ++j) {
                int cb = colw + j * 4;               // 4 cols per instruction
                int col = cb + q;
                int gchunk = lm ^ (col & 7);
                const short* gp = whtb + (long)col * 4096 + m0 + gchunk * 8;
                short* lp = tile + cb * 128;         // wave-uniform base; lane lands at +16*l
                __builtin_amdgcn_global_load_lds(
                    (const __attribute__((address_space(1))) void*)gp,
                    (__attribute__((address_space(3))) void*)lp,
                    16, 0, 0);
            }
        }
        // per-tile adj + t prefetch (full cache lines: 16 rows x 128B per k-step)
        i32x4 aj[8];
        f32x4 tv[8];
        #pragma unroll
        for (int ks = 0; ks < 4; ++ks) {
            int bm = m0 + ks * 32 + q * 8;
            aj[2 * ks]     = *(const i32x4*)(adjrow + bm);
            aj[2 * ks + 1] = *(const i32x4*)(adjrow + bm + 4);
            tv[2 * ks]     = *(const f32x4*)(tpb + bm);
            tv[2 * ks + 1] = *(const f32x4*)(tpb + bm + 4);
        }
        __syncthreads();   // stage visible (compiler drains vmcnt before barrier)

        #pragma unroll
        for (int ks = 0; ks < 4; ++ks) {
            s16x8 af;
            float zs = 0.0f;
            #pragma unroll
            for (int half = 0; half < 2; ++half) {
                i32x4 a4 = aj[2 * ks + half];
                f32x4 t4 = tv[2 * ks + half];
                #pragma unroll
                for (int j = 0; j < 4; ++j) {
                    float y = sp + t4[j];
                    float e = fmaxf(y, 0.2f * y) - Mrow;   // scaled leakyrelu - max
                    float wv = exp2f(e);
                    wv = (a4[j] != 0) ? wv : 0.0f;
                    zs += wv;
                    af[half * 4 + j] = f32_to_bf16_rne(wv);
                }
            }
            z += zs;
            bf16x8 afb = as_bf16x8(af);
            #pragma unroll
            for (int ct = 0; ct < 8; ++ct) {
                int col = ct * 16 + lm;
                int pos = (ks * 4 + q) ^ (col & 7);
                s16x8 bf = *(const s16x8*)(tile + col * 128 + pos * 8);
                acc[ct] = __builtin_amdgcn_mfma_f32_16x16x32_bf16(afb, as_bf16x8(bf), acc[ct], 0, 0, 0);
            }
        }
    }

    // Z reduction: lanes {lm, lm+16, lm+32, lm+48} hold partials of row lm
    z += __shfl_xor(z, 16);
    z += __shfl_xor(z, 32);

    if (DIRECT) {
        float zr[4];
        #pragma unroll
        for (int r = 0; r < 4; ++r) zr[r] = __shfl(z, q * 4 + r);  // Z for C-row q*4+r
        float* orow = out + (long)(b * 4096 + n0 + w * 16) * 128;
        #pragma unroll
        for (int ct = 0; ct < 8; ++ct) {
            int col = ct * 16 + lm;
            #pragma unroll
            for (int r = 0; r < 4; ++r) {
                float x = acc[ct][r] / zr[r];
                orow[(q * 4 + r) * 128 + col] = (x > 0.f) ? x : (expf(x) - 1.0f);
            }
        }
    } else {
        if (l < 16) Z[(b * SPLIT + mh) * 4096 + n0 + w * 16 + lm] = z;
        float* ub = U + ((long)(b * SPLIT + mh) * 4096 + n0 + w * 16) * 128;
        #pragma unroll
        for (int ct = 0; ct < 8; ++ct) {
            int col = ct * 16 + lm;
            #pragma unroll
            for (int r = 0; r < 4; ++r)
                ub[(q * 4 + r) * 128 + col] = acc[ct][r];
        }
    }
}

// ---------------- k4: combine split-m halves + ELU ----------------
__global__ void k4_combine(const float* __restrict__ U, const float* __restrict__ Z,
                           float* __restrict__ out) {
    long g = (long)blockIdx.x * 256 + threadIdx.x;   // float4 index
    long off = g * 4;
    long nf = off >> 7;                               // b*4096+n
    int b = (int)(nf >> 12), n = (int)(nf & 4095), col = (int)(off & 127);
    long base0 = ((long)(b * 2) * 4096 + n) * 128 + col;
    f32x4 u0 = *(const f32x4*)(U + base0);
    f32x4 u1 = *(const f32x4*)(U + base0 + (long)4096 * 128);
    float zz = Z[(b * 2) * 4096 + n] + Z[(b * 2 + 1) * 4096 + n];
    f32x4 v;
    #pragma unroll
    for (int i = 0; i < 4; ++i) {
        float x = (u0[i] + u1[i]) / zz;
        v[i] = (x > 0.f) ? x : (expf(x) - 1.0f);
    }
    *(f32x4*)(out + off) = v;
}

extern "C" void kernel_launch(void* const* d_in, const int* in_sizes, int n_in,
                              void* d_out, int out_size, void* d_ws, size_t ws_size,
                              hipStream_t stream) {
    const float* h   = (const float*)d_in[0];
    const int*   adj = (const int*)d_in[1];
    const float* W   = (const float*)d_in[2];
    const float* a   = (const float*)d_in[3];
    float* out = (float*)d_out;

    char* ws = (char*)d_ws;
    short* WhT  = (short*)ws;                          // 4 MB  bf16 [b][col][n]
    short* WT   = (short*)(ws + 4194304);              // 64 KB bf16 [col][k]
    float* Wh1p = (float*)(ws + 4259840);              // 64 KB log2e*Wh@a1
    float* Tp   = (float*)(ws + 4325376);              // 64 KB log2e*Wh@a2
    float* Tmax = (float*)(ws + 4390912);              // 16 B (+pad)
    float* U    = (float*)(ws + 4391168);              // 16 MB (split=2)
    float* Z    = (float*)(ws + 4391168 + 16777216);   // 128 KB

    k0_wt<<<32, 256, 0, stream>>>(W, WT);
    k1_gemm<<<256, 256, 0, stream>>>(h, a, WT, WhT, Wh1p, Tp);
    k2_tmax<<<4, 256, 0, stream>>>(Tp, Tmax);

    bool split2 = ws_size >= (size_t)(4391168 + 16777216 + 131072);
    if (split2) {
        k3_attn<2, false><<<512, 256, 0, stream>>>(adj, WhT, Wh1p, Tp, Tmax, U, Z, out);
        k4_combine<<<2048, 256, 0, stream>>>(U, Z, out);
    } else {
        k3_attn<1, true><<<256, 256, 0, stream>>>(adj, WhT, Wh1p, Tp, Tmax, nullptr, nullptr, out);
    }
    (void)in_sizes; (void)n_in; (void)out_size;
}